// Round 1
// 108.200 us; speedup vs baseline: 1.1156x; 1.1156x over previous
//
#include <hip/hip_runtime.h>
#include <hip/hip_bf16.h>
#include <cstdint>

#define N_PTS 8192
#define DIM 128

typedef __attribute__((ext_vector_type(8))) __bf16 bf16x8;
typedef __attribute__((ext_vector_type(4))) float f32x4;

// Base-2-domain circle-loss constants (gamma=256, m=0.25, folded log2(e)).
// lp_nat = (1.25-s)(0.75-s)*256 = 256 s^2 - 512 s + 240   (1.25-s>0 always: |s|<=~1.01)
// ln_nat = max(s+0.25,0)*(s-0.25)*256 = (s>-0.25) ? 256 s^2 - 16 : 0
#define KC2 369.3299304675746f    //  256*log2e
#define KC1 -738.6598609351493f   // -512*log2e
#define KC0 346.2468098133512f    //  240*log2e
#define KCN0 -23.083120654223414f // -16*log2e
#define NEGH -1e30f
#define LN2F 0.6931471805599453f

// RNE float -> bf16 bits (inputs are finite, no NaN handling needed)
__device__ __forceinline__ unsigned short f2bf(float x) {
  unsigned int u = __float_as_uint(x);
  unsigned int r = (u + 0x7FFFu + ((u >> 16) & 1u)) >> 16;
  return (unsigned short)r;
}

// One wave per row: L2-normalize (eps=1e-12) and store bf16 bits.
__global__ __launch_bounds__(256) void normalize_kernel(const float* __restrict__ feat,
                                                        unsigned short* __restrict__ fb) {
  const int row = blockIdx.x * 4 + (threadIdx.x >> 6);
  const int lane = threadIdx.x & 63;
  const float2 v = *(const float2*)(feat + row * DIM + lane * 2);
  float ss = v.x * v.x + v.y * v.y;
#pragma unroll
  for (int o = 32; o > 0; o >>= 1) ss += __shfl_xor(ss, o);
  const float inv = 1.0f / fmaxf(sqrtf(ss), 1e-12f);
  const unsigned int pack =
      (unsigned int)f2bf(v.x * inv) | ((unsigned int)f2bf(v.y * inv) << 16);
  *(unsigned int*)(fb + row * DIM + lane * 2) = pack;
}

// 128x128 output tile per block (4 waves, each 64x64 = 4x4 MFMA tiles of 16x16).
// Computes sim = f @ f^T for the tile, then per-block logsumexp partials in
// base-2 domain. partials[slot] = (M2p, S2p, M2n, S2n).
__global__ __launch_bounds__(256) void pair_kernel(const unsigned short* __restrict__ f,
                                                   const int* __restrict__ labels,
                                                   float4* __restrict__ partials) {
  const int tI = blockIdx.y, tJ = blockIdx.x;
  const int slot = tI * 64 + tJ;
  if (tJ < tI) {  // lower triangle: neutral partial
    if (threadIdx.x == 0) partials[slot] = make_float4(NEGH, 0.f, NEGH, 0.f);
    return;
  }

  __shared__ __align__(16) unsigned short sA[128 * 32];
  __shared__ __align__(16) unsigned short sB[128 * 32];
  __shared__ float redbuf[8];

  const int t = threadIdx.x;
  const int lane = t & 63, wave = t >> 6;
  const int wr = (wave >> 1) * 64, wc = (wave & 1) * 64;
  const int rsel = lane & 15, ksel = (lane >> 4) * 8;

  f32x4 acc[4][4];
#pragma unroll
  for (int a = 0; a < 4; ++a)
#pragma unroll
    for (int b = 0; b < 4; ++b) acc[a][b] = (f32x4){0.f, 0.f, 0.f, 0.f};

  const int rowA0 = tI * 128, rowB0 = tJ * 128;

  for (int kk = 0; kk < 4; ++kk) {
    const int k0 = kk * 32;
    if (kk) __syncthreads();
#pragma unroll
    for (int c0 = 0; c0 < 2; ++c0) {
      const int c = t + c0 * 256;           // 512 16B chunks per 128x32 slab
      const int r = c >> 2, e = (c & 3) * 8;
      *(uint4*)(&sA[r * 32 + e]) = *(const uint4*)(f + (rowA0 + r) * DIM + k0 + e);
      *(uint4*)(&sB[r * 32 + e]) = *(const uint4*)(f + (rowB0 + r) * DIM + k0 + e);
    }
    __syncthreads();
    bf16x8 fa[4], fbv[4];
#pragma unroll
    for (int x = 0; x < 4; ++x) {
      fa[x] = *(const bf16x8*)(&sA[(wr + x * 16 + rsel) * 32 + ksel]);
      fbv[x] = *(const bf16x8*)(&sB[(wc + x * 16 + rsel) * 32 + ksel]);
    }
#pragma unroll
    for (int tm = 0; tm < 4; ++tm)
#pragma unroll
      for (int tn = 0; tn < 4; ++tn)
        acc[tm][tn] =
            __builtin_amdgcn_mfma_f32_16x16x32_bf16(fa[tm], fbv[tn], acc[tm][tn], 0, 0, 0);
  }

  // ---- epilogue: circle-loss logits (base-2 domain) + logsumexp ----
  // C/D mapping (16x16x32): col = lane&15, row = (lane>>4)*4 + reg
  const int ibase = tI * 128 + wr + (lane >> 4) * 4;
  const int jbase = tJ * 128 + wc + rsel;
  int li[4][4], lj[4];
#pragma unroll
  for (int tn = 0; tn < 4; ++tn) lj[tn] = labels[jbase + tn * 16];
#pragma unroll
  for (int tm = 0; tm < 4; ++tm)
#pragma unroll
    for (int r = 0; r < 4; ++r) li[tm][r] = labels[ibase + tm * 16 + r];

  // pass 1: compute selected logit in-place, track per-thread maxes
  float mp = NEGH, mn = NEGH;
  if (tI != tJ) {  // all pairs valid (j > i globally)
#pragma unroll
    for (int tm = 0; tm < 4; ++tm)
#pragma unroll
      for (int tn = 0; tn < 4; ++tn)
#pragma unroll
        for (int r = 0; r < 4; ++r) {
          const float s = acc[tm][tn][r];
          const float w = s * KC2;
          const float lp = fmaf(s, w + KC1, KC0);
          const float ln = (s > -0.25f) ? fmaf(s, w, KCN0) : 0.f;
          const bool eq = (li[tm][r] == lj[tn]);
          acc[tm][tn][r] = eq ? lp : ln;
          mp = fmaxf(mp, eq ? lp : NEGH);
          mn = fmaxf(mn, eq ? NEGH : ln);
        }
  } else {  // diagonal tile: mask out j <= i
#pragma unroll
    for (int tm = 0; tm < 4; ++tm)
#pragma unroll
      for (int tn = 0; tn < 4; ++tn) {
        const int d = (jbase + tn * 16) - (ibase + tm * 16);  // valid iff d > r
#pragma unroll
        for (int r = 0; r < 4; ++r) {
          const float s = acc[tm][tn][r];
          const float w = s * KC2;
          const float lp = fmaf(s, w + KC1, KC0);
          const float ln = (s > -0.25f) ? fmaf(s, w, KCN0) : 0.f;
          const bool eq = (li[tm][r] == lj[tn]);
          const bool valid = d > r;
          float u = eq ? lp : ln;
          u = valid ? u : NEGH;
          acc[tm][tn][r] = u;
          mp = fmaxf(mp, (eq && valid) ? lp : NEGH);
          mn = fmaxf(mn, (!eq && valid) ? ln : NEGH);
        }
      }
  }
#pragma unroll
  for (int o = 32; o > 0; o >>= 1) {
    mp = fmaxf(mp, __shfl_xor(mp, o));
    mn = fmaxf(mn, __shfl_xor(mn, o));
  }
  if (lane == 0) { redbuf[wave] = mp; redbuf[4 + wave] = mn; }
  __syncthreads();
  // Clamp: keeps exp2(NEGH - M) == 0 even when a stream is empty in this block.
  const float Mp = fmaxf(fmaxf(fmaxf(redbuf[0], redbuf[1]), fmaxf(redbuf[2], redbuf[3])), -1e28f);
  const float Mn = fmaxf(fmaxf(fmaxf(redbuf[4], redbuf[5]), fmaxf(redbuf[6], redbuf[7])), -1e28f);
  __syncthreads();  // protect redbuf before reuse for sums

  // pass 2: one exp2 per element, route to the owning stream
  float sp = 0.f, sn = 0.f;
#pragma unroll
  for (int tm = 0; tm < 4; ++tm)
#pragma unroll
    for (int tn = 0; tn < 4; ++tn)
#pragma unroll
      for (int r = 0; r < 4; ++r) {
        const bool eq = (li[tm][r] == lj[tn]);
        const float e = __builtin_amdgcn_exp2f(acc[tm][tn][r] - (eq ? Mp : Mn));
        sp += eq ? e : 0.f;
        sn += eq ? 0.f : e;
      }
#pragma unroll
  for (int o = 32; o > 0; o >>= 1) {
    sp += __shfl_xor(sp, o);
    sn += __shfl_xor(sn, o);
  }
  if (lane == 0) { redbuf[wave] = sp; redbuf[4 + wave] = sn; }
  __syncthreads();
  if (t == 0) {
    partials[slot] = make_float4(Mp, redbuf[0] + redbuf[1] + redbuf[2] + redbuf[3],
                                 Mn, redbuf[4] + redbuf[5] + redbuf[6] + redbuf[7]);
  }
}

// Merge 4096 (m2,s2) base-2 partials for both streams; softplus(lse_p + lse_n).
__global__ __launch_bounds__(256) void finalize_kernel(const float4* __restrict__ partials,
                                                       float* __restrict__ out) {
  const int t = threadIdx.x;
  float mp = NEGH, sp = 0.f, mn = NEGH, sn = 0.f;
  for (int i = t; i < 4096; i += 256) {
    const float4 p = partials[i];
    {
      const float m = fmaxf(mp, p.x);
      sp = sp * __builtin_amdgcn_exp2f(mp - m) + p.y * __builtin_amdgcn_exp2f(p.x - m);
      mp = m;
    }
    {
      const float m = fmaxf(mn, p.z);
      sn = sn * __builtin_amdgcn_exp2f(mn - m) + p.w * __builtin_amdgcn_exp2f(p.z - m);
      mn = m;
    }
  }
  __shared__ float smp[256], ssp[256], smn[256], ssn[256];
  smp[t] = mp; ssp[t] = sp; smn[t] = mn; ssn[t] = sn;
  __syncthreads();
  for (int off = 128; off > 0; off >>= 1) {
    if (t < off) {
      {
        const float m2 = smp[t + off], s2 = ssp[t + off];
        const float m = fmaxf(smp[t], m2);
        ssp[t] = ssp[t] * __builtin_amdgcn_exp2f(smp[t] - m) + s2 * __builtin_amdgcn_exp2f(m2 - m);
        smp[t] = m;
      }
      {
        const float m2 = smn[t + off], s2 = ssn[t + off];
        const float m = fmaxf(smn[t], m2);
        ssn[t] = ssn[t] * __builtin_amdgcn_exp2f(smn[t] - m) + s2 * __builtin_amdgcn_exp2f(m2 - m);
        smn[t] = m;
      }
    }
    __syncthreads();
  }
  if (t == 0) {
    // convert base-2 lse back to natural log
    const float lsep = (smp[0] + __builtin_amdgcn_logf(ssp[0])) * LN2F;
    const float lsen = (smn[0] + __builtin_amdgcn_logf(ssn[0])) * LN2F;
    const float x = lsep + lsen;
    out[0] = fmaxf(x, 0.f) + log1pf(__expf(-fabsf(x)));  // stable softplus
  }
}

extern "C" void kernel_launch(void* const* d_in, const int* in_sizes, int n_in,
                              void* d_out, int out_size, void* d_ws, size_t ws_size,
                              hipStream_t stream) {
  const float* feat = (const float*)d_in[0];
  const int* labels = (const int*)d_in[1];
  float* out = (float*)d_out;

  unsigned short* fb = (unsigned short*)d_ws;                        // 8192*128*2 = 2 MB
  float4* partials = (float4*)((char*)d_ws + (size_t)N_PTS * DIM * 2);  // 4096*16 = 64 KB

  normalize_kernel<<<N_PTS / 4, 256, 0, stream>>>(feat, fb);
  dim3 grid(64, 64);
  pair_kernel<<<grid, 256, 0, stream>>>(fb, labels, partials);
  finalize_kernel<<<1, 256, 0, stream>>>(partials, out);
}